// Round 7
// baseline (1525.017 us; speedup 1.0000x reference)
//
#include <hip/hip_runtime.h>
#include <hip/hip_bf16.h>

#define AA 64
#define NBRF 41
#define ORIGD 92
#define NATOM 50000
#define MM 12
#define NB 1000
#define NPCC 50
#define NEDGE (NATOM*MM)
#define ATB 8            // atoms per pass-block
#define EPB 96           // edges per pass-block
#define BT 384           // threads per pass-block (6 waves)
#define NPBLK (NATOM/ATB) // 6250
constexpr float EPS_BN = 1e-5f;

using bf16 = __hip_bfloat16;
typedef short s16x8 __attribute__((ext_vector_type(8)));
typedef float f32x4 __attribute__((ext_vector_type(4)));

__device__ __forceinline__ float u2f(unsigned short u) {
    union { float f; unsigned int i; } v; v.i = ((unsigned int)u) << 16; return v.f;
}
__device__ __forceinline__ unsigned short f2bu(float f) {
    bf16 h = __float2bfloat16(f);
    return *reinterpret_cast<unsigned short*>(&h);
}
__device__ __forceinline__ float fsigmoid(float x) {
    float e = __expf(-x);
    return __builtin_amdgcn_rcpf(1.f + e);
}
__device__ __forceinline__ float fsoftplus(float x) {
    return fmaxf(x, 0.f) + __logf(1.f + __expf(-fabsf(x)));
}

// ---------------- zero small stats region ----------------
__global__ void k_zero(float* p, int n) {
    int i = blockIdx.x * blockDim.x + threadIdx.x;
    if (i < n) p[i] = 0.f;
}

// ---------------- prep: W(169x128) -> Bt3 bf16 [3 chunks][128 n][72 k] ----------------
// chunk0 = W rows 0..63 (self), chunk1 = rows 64..127 (neighbor), chunk2 = rows 128..168 (nf, pad)
__global__ void k_prepB3(const float* __restrict__ W, unsigned short* __restrict__ Bt3) {
    int i = blockIdx.x * 256 + threadIdx.x; // 3*128*72 = 27648
    if (i >= 3 * 128 * 72) return;
    int chunk = i / (128 * 72), r = i - chunk * (128 * 72);
    int n = r / 72, k = r - n * 72;
    int krow = chunk * 64 + k;
    float v = (krow < 169 && (chunk < 2 || k < NBRF)) ? W[(size_t)krow * 128 + n] : 0.f;
    Bt3[i] = f2bu(v);
}

// ---------------- prep: nbr_fea -> nfb bf16 [NEDGE][72] (41 + zero pad) ----------------
__global__ void k_prepN(const float* __restrict__ nf, unsigned short* __restrict__ nfb) {
    int i = blockIdx.x * 256 + threadIdx.x; // < NEDGE*72
    int m = i / 72, k = i - m * 72;
    nfb[i] = (k < NBRF) ? f2bu(nf[(size_t)m * NBRF + k]) : (unsigned short)0;
}

// ---------------- prep: adj_w -> Bq bf16 [384 rows(n=o*64+e)][72 (k=d, padded)] ----------------
__global__ void k_prepQ(const float* __restrict__ adjw, unsigned short* __restrict__ Bq) {
    int i = blockIdx.x * 256 + threadIdx.x; // 384*72 = 27648
    if (i >= 384 * 72) return;
    int n = i / 72, k = i - n * 72;
    float v = (k < 64) ? adjw[(n >> 6) * 4096 + k * 64 + (n & 63)] : 0.f;
    Bq[i] = f2bu(v);
}

// ---------------- embed: x = atom_fea @ emb_w  (N,92)@(92,64); also xb bf16 ----------------
__global__ __launch_bounds__(256) void k_embed(const float* __restrict__ af,
                                               const float* __restrict__ w,
                                               float* __restrict__ x,
                                               unsigned short* __restrict__ xb) {
    __shared__ float wl[ORIGD * AA];
    __shared__ float al[4][ORIGD];
    int t = threadIdx.x;
    for (int i = t; i < ORIGD * AA; i += 256) wl[i] = w[i];
    int n0 = blockIdx.x * 4;
    for (int i = t; i < 4 * ORIGD; i += 256) {
        int a = i / ORIGD, k = i - a * ORIGD;
        al[a][k] = af[(size_t)(n0 + a) * ORIGD + k];
    }
    __syncthreads();
    int c = t & 63, a = t >> 6;
    float acc = 0.f;
    #pragma unroll 4
    for (int k = 0; k < ORIGD; ++k)
        acc += al[a][k] * wl[k * AA + c];
    x[(size_t)(n0 + a) * AA + c] = acc;
    xb[(size_t)(n0 + a) * AA + c] = f2bu(acc);
}

// ================= fused MFMA edge pass A =================
// gated[m] = x[a(m)]@W0 + x[g(m)]@W1 + nf[m]@W2   (all bf16 MFMA, fp32 acc)
// 8 atoms (96 edges) per block, 6 waves = 6 m-tiles. N processed in two 64-col halves.

__device__ __forceinline__ void stage_Bh(int t, int half, const unsigned short* __restrict__ Bt3,
                                         unsigned short* Bh) {
    const uint4* src = reinterpret_cast<const uint4*>(Bt3);
    uint4* dst = reinterpret_cast<uint4*>(Bh);
    for (int i = t; i < 1728; i += BT) {           // 3 chunks * 64 rows * 9 uint4
        int chunk = i / 576, r = i - chunk * 576;
        int nn = r / 9, c = r - nn * 9;
        dst[i] = src[chunk * 1152 + (half * 64 + nn) * 9 + c];
    }
}

template<bool USE_NFB>
__global__ __launch_bounds__(BT, 3) void k_passA(const unsigned short* __restrict__ xb,
                                                 const float* __restrict__ nf,
                                                 const unsigned short* __restrict__ nfb,
                                                 const unsigned short* __restrict__ Bt3,
                                                 const int* __restrict__ nidx,
                                                 float* __restrict__ stats,
                                                 uint2* __restrict__ gated) {
    __shared__ __attribute__((aligned(16))) unsigned short Ag[EPB * 72];   // 13824B gathered x[g]
    __shared__ __attribute__((aligned(16))) unsigned short An[EPB * 72];   // 13824B nf
    __shared__ __attribute__((aligned(16))) unsigned short Ax[16 * 72];    // 2304B  x[self] (8 used)
    __shared__ __attribute__((aligned(16))) unsigned short Bh[3 * 64 * 72];// 27648B current half
    __shared__ float y0l[ATB * 128];                                       // 4096B  self-term
    int t = threadIdx.x;
    int w = t >> 6, lane = t & 63, ln = lane & 15, quad = lane >> 4;
    int n0 = blockIdx.x * ATB;
    int e0 = n0 * MM;

    // ---- stage ----
    for (int i = t; i < EPB * 8; i += BT) {        // x-gather: 96 rows x 8 uint4
        int m = i >> 3, c = i & 7;
        int g = nidx[e0 + m];
        *reinterpret_cast<uint4*>(&Ag[m * 72 + c * 8]) =
            *reinterpret_cast<const uint4*>(&xb[(size_t)g * AA + c * 8]);
    }
    if (USE_NFB) {
        const uint4* src = reinterpret_cast<const uint4*>(nfb + (size_t)e0 * 72);
        uint4* dst = reinterpret_cast<uint4*>(An);
        for (int i = t; i < EPB * 9; i += BT) dst[i] = src[i];
    } else {
        for (int i = t; i < EPB * 72; i += BT) {
            int m = i / 72, k = i - m * 72;
            An[i] = (k < NBRF) ? f2bu(nf[(size_t)(e0 + m) * NBRF + k]) : (unsigned short)0;
        }
    }
    if (t < ATB * 8) {
        int a = t >> 3, c = t & 7;
        *reinterpret_cast<uint4*>(&Ax[a * 72 + c * 8]) =
            *reinterpret_cast<const uint4*>(&xb[(size_t)(n0 + a) * AA + c * 8]);
    }
    stage_Bh(t, 0, Bt3, Bh);
    __syncthreads();

    uint2* gblk = gated + (size_t)blockIdx.x * (8 * BT);
    float s[8] = {0,0,0,0,0,0,0,0}, q[8] = {0,0,0,0,0,0,0,0};
    int mrow = w * 16 + ln;
    f32x4 z4 = {0.f, 0.f, 0.f, 0.f};

    #pragma unroll
    for (int half = 0; half < 2; ++half) {
        // self-term tile (wave 0): Ax @ W0-half -> y0l
        if (w == 0) {
            s16x8 ax0 = *reinterpret_cast<const s16x8*>(&Ax[ln * 72 + quad * 8]);
            s16x8 ax1 = *reinterpret_cast<const s16x8*>(&Ax[ln * 72 + quad * 8 + 32]);
            #pragma unroll
            for (int nt = 0; nt < 4; ++nt) {
                int nrow = nt * 16 + ln;
                s16x8 b0 = *reinterpret_cast<const s16x8*>(&Bh[nrow * 72 + quad * 8]);
                s16x8 b1 = *reinterpret_cast<const s16x8*>(&Bh[nrow * 72 + quad * 8 + 32]);
                f32x4 ay = __builtin_amdgcn_mfma_f32_16x16x32_bf16(ax0, b0, z4, 0, 0, 0);
                ay = __builtin_amdgcn_mfma_f32_16x16x32_bf16(ax1, b1, ay, 0, 0, 0);
                #pragma unroll
                for (int reg = 0; reg < 4; ++reg) {
                    int row = quad * 4 + reg;
                    if (row < ATB) y0l[row * 128 + half * 64 + nt * 16 + ln] = ay[reg];
                }
            }
        }
        // main: x[g]@W1 + nf@W2
        s16x8 ag0 = *reinterpret_cast<const s16x8*>(&Ag[mrow * 72 + quad * 8]);
        s16x8 ag1 = *reinterpret_cast<const s16x8*>(&Ag[mrow * 72 + quad * 8 + 32]);
        s16x8 an0 = *reinterpret_cast<const s16x8*>(&An[mrow * 72 + quad * 8]);
        s16x8 an1 = *reinterpret_cast<const s16x8*>(&An[mrow * 72 + quad * 8 + 32]);
        f32x4 acc[4];
        #pragma unroll
        for (int nt = 0; nt < 4; ++nt) {
            int nrow = nt * 16 + ln;
            const unsigned short* B1 = Bh + 64 * 72;
            const unsigned short* B2 = Bh + 2 * 64 * 72;
            s16x8 b0 = *reinterpret_cast<const s16x8*>(&B1[nrow * 72 + quad * 8]);
            s16x8 b1 = *reinterpret_cast<const s16x8*>(&B1[nrow * 72 + quad * 8 + 32]);
            acc[nt] = __builtin_amdgcn_mfma_f32_16x16x32_bf16(ag0, b0, z4, 0, 0, 0);
            acc[nt] = __builtin_amdgcn_mfma_f32_16x16x32_bf16(ag1, b1, acc[nt], 0, 0, 0);
            s16x8 c0 = *reinterpret_cast<const s16x8*>(&B2[nrow * 72 + quad * 8]);
            s16x8 c1 = *reinterpret_cast<const s16x8*>(&B2[nrow * 72 + quad * 8 + 32]);
            acc[nt] = __builtin_amdgcn_mfma_f32_16x16x32_bf16(an0, c0, acc[nt], 0, 0, 0);
            acc[nt] = __builtin_amdgcn_mfma_f32_16x16x32_bf16(an1, c1, acc[nt], 0, 0, 0);
        }
        __syncthreads();   // y0l visible; Bh reads done
        if (half == 0) stage_Bh(t, 1, Bt3, Bh);   // overlap restage with epilogue
        // epilogue: add self-term, stats, pack gated
        #pragma unroll
        for (int reg = 0; reg < 4; ++reg) {
            int m = w * 16 + quad * 4 + reg;
            int a = m / MM;
            float v[4];
            #pragma unroll
            for (int nt = 0; nt < 4; ++nt) {
                int c = half * 64 + nt * 16 + ln;
                float r = acc[nt][reg] + y0l[a * 128 + c];
                v[nt] = r;
                s[half * 4 + nt] += r; q[half * 4 + nt] += r * r;
            }
            uint2 u;
            u.x = (unsigned)f2bu(v[0]) | ((unsigned)f2bu(v[1]) << 16);
            u.y = (unsigned)f2bu(v[2]) | ((unsigned)f2bu(v[3]) << 16);
            gblk[(half * 4 + reg) * BT + t] = u;
        }
        __syncthreads();   // Bh(half1) staged; y0l free for overwrite
    }
    // stats reduce: shuffle over quads, then LDS (alias Ag), then atomics
    #pragma unroll
    for (int j = 0; j < 8; ++j) {
        s[j] += __shfl_xor(s[j], 16); s[j] += __shfl_xor(s[j], 32);
        q[j] += __shfl_xor(q[j], 16); q[j] += __shfl_xor(q[j], 32);
    }
    float* red = reinterpret_cast<float*>(Ag); // [2][6 waves][8 j][16 ln]
    if (quad == 0) {
        #pragma unroll
        for (int j = 0; j < 8; ++j) {
            red[w * 128 + j * 16 + ln] = s[j];
            red[768 + w * 128 + j * 16 + ln] = q[j];
        }
    }
    __syncthreads();
    if (t < 256) {
        int sel = t >> 7, c = t & 127;
        int j = (c >> 6) * 4 + ((c >> 4) & 3), l2 = c & 15;
        float v = 0.f;
        #pragma unroll
        for (int w2 = 0; w2 < 6; ++w2)
            v += red[sel * 768 + w2 * 128 + j * 16 + l2];
        atomicAdd(&stats[sel * 128 + c], v);
    }
}

// ---------------- bn1 fold ----------------
__global__ void k_sc1(const float* __restrict__ stats, const float* __restrict__ g,
                      const float* __restrict__ b, float* __restrict__ sc) {
    int c = threadIdx.x; // 128
    float cnt = (float)NEDGE;
    float mean = stats[c] / cnt;
    float var = stats[128 + c] / cnt - mean * mean;
    float inv = rsqrtf(var + EPS_BN);
    float scale = g[c] * inv;
    sc[c] = scale;
    sc[128 + c] = b[c] - mean * scale;
}

// ---------------- pass B (streaming): read gated, BN1+act, sum over neighbors ----------------
__global__ __launch_bounds__(BT) void k_passBs(const uint2* __restrict__ gated,
                                               const float* __restrict__ sc,
                                               float* __restrict__ summed,
                                               float* __restrict__ stats2) {
    __shared__ unsigned short P[EPB * 66]; // 12672B
    __shared__ float sred[128];
    int t = threadIdx.x;
    int n0 = blockIdx.x * ATB;
    int w = t >> 6, lane = t & 63, ln = lane & 15, quad = lane >> 4;
    float scF[4], shF[4], scC[4], shC[4];
    #pragma unroll
    for (int nt = 0; nt < 4; ++nt) {
        int cc = nt * 16 + ln;
        scF[nt] = sc[cc];      shF[nt] = sc[128 + cc];
        scC[nt] = sc[64 + cc]; shC[nt] = sc[192 + cc];
    }
    const uint2* gblk = gated + (size_t)blockIdx.x * (8 * BT);
    #pragma unroll
    for (int reg = 0; reg < 4; ++reg) {
        uint2 u0 = gblk[reg * BT + t];           // half0 = filter cols
        uint2 u1 = gblk[(4 + reg) * BT + t];     // half1 = core cols
        int m = w * 16 + quad * 4 + reg;
        unsigned f01 = u0.x, f23 = u0.y, c01 = u1.x, c23 = u1.y;
        #pragma unroll
        for (int nt = 0; nt < 4; ++nt) {
            unsigned fu = (nt < 2) ? f01 : f23;
            unsigned cu = (nt < 2) ? c01 : c23;
            float rfv = u2f((unsigned short)((nt & 1) ? (fu >> 16) : (fu & 0xffff)));
            float rcv = u2f((unsigned short)((nt & 1) ? (cu >> 16) : (cu & 0xffff)));
            float rf = rfv * scF[nt] + shF[nt];
            float rc = rcv * scC[nt] + shC[nt];
            P[m * 66 + nt * 16 + ln] = f2bu(fsigmoid(rf) * fsoftplus(rc));
        }
    }
    if (t < 128) sred[t] = 0.f;
    __syncthreads();
    for (int idx = t; idx < ATB * 64; idx += BT) {
        int a = idx >> 6, c = idx & 63;
        float v = 0.f;
        #pragma unroll
        for (int j = 0; j < 12; ++j) v += u2f(P[(a * 12 + j) * 66 + c]);
        summed[(size_t)(n0 + a) * AA + c] = v;
        atomicAdd(&sred[c], v);
        atomicAdd(&sred[64 + c], v * v);
    }
    __syncthreads();
    if (t < 128) atomicAdd(&stats2[t], sred[t]);
}

// ---------------- bn2 fold ----------------
__global__ void k_sc2(const float* __restrict__ stats2, const float* __restrict__ g,
                      const float* __restrict__ b, float* __restrict__ sc2) {
    int c = threadIdx.x; // 64
    float cnt = (float)NATOM;
    float mean = stats2[c] / cnt;
    float var = stats2[64 + c] / cnt - mean * mean;
    float inv = rsqrtf(var + EPS_BN);
    float scale = g[c] * inv;
    sc2[c] = scale;
    sc2[64 + c] = b[c] - mean * scale;
}

// ---------------- x = softplus(x + bn2(summed)); also xb ----------------
__global__ void k_update(float* __restrict__ x, unsigned short* __restrict__ xb,
                         const float* __restrict__ summed, const float* __restrict__ sc2) {
    int i = blockIdx.x * blockDim.x + threadIdx.x;
    if (i < NATOM * AA) {
        int c = i & 63;
        float s = summed[i] * sc2[c] + sc2[64 + c];
        float v = fsoftplus(x[i] + s);
        x[i] = v;
        xb[i] = f2bu(v);
    }
}

// ---------------- bilinear head via MFMA ----------------
__global__ __launch_bounds__(256) void k_q(const float* __restrict__ x, const int* __restrict__ cidx,
                                           const unsigned short* __restrict__ Bq, // 384x72 bf16
                                           const float* __restrict__ adjb,
                                           const float* __restrict__ fc1w,
                                           const float* __restrict__ fc1b,
                                           float* __restrict__ logp) {
    __shared__ __attribute__((aligned(16))) unsigned short Aq[64 * 72];  // 9216B
    __shared__ __attribute__((aligned(16))) unsigned short Bl[384 * 72]; // 55296B
    __shared__ float qv[64][6];
    int t = threadIdx.x;
    int p0 = blockIdx.x * 64;
    for (int i = t; i < 64 * 72; i += 256) {
        int a = i / 72, k = i - a * 72;
        int ga = p0 + a;
        float v = (k < 64 && ga < NATOM) ? x[(size_t)cidx[ga < NATOM ? ga : 0] * AA + k] : 0.f;
        Aq[i] = f2bu(v);
    }
    for (int i = t; i < 3456; i += 256)
        reinterpret_cast<uint4*>(Bl)[i] = reinterpret_cast<const uint4*>(Bq)[i];
    __syncthreads();

    int w = t >> 6, lane = t & 63, ln = lane & 15, quad = lane >> 4;
    f32x4 acc[24];
    f32x4 z4 = {0.f, 0.f, 0.f, 0.f};
    #pragma unroll
    for (int i = 0; i < 24; ++i) acc[i] = z4;
    {
        int mrow = w * 16 + ln;
        s16x8 a0 = *reinterpret_cast<const s16x8*>(&Aq[mrow * 72 + quad * 8]);
        s16x8 a1 = *reinterpret_cast<const s16x8*>(&Aq[mrow * 72 + quad * 8 + 32]);
        #pragma unroll
        for (int nt = 0; nt < 24; ++nt) {
            int nrow = nt * 16 + ln;
            s16x8 b0 = *reinterpret_cast<const s16x8*>(&Bl[nrow * 72 + quad * 8]);
            s16x8 b1 = *reinterpret_cast<const s16x8*>(&Bl[nrow * 72 + quad * 8 + 32]);
            acc[nt] = __builtin_amdgcn_mfma_f32_16x16x32_bf16(a0, b0, acc[nt], 0, 0, 0);
            acc[nt] = __builtin_amdgcn_mfma_f32_16x16x32_bf16(a1, b1, acc[nt], 0, 0, 0);
        }
    }
    float cfv[4][4];
    #pragma unroll
    for (int reg = 0; reg < 4; ++reg) {
        int ga = p0 + w * 16 + quad * 4 + reg;
        const float* xr = x + (size_t)cidx[ga < NATOM ? ga : 0] * AA;
        #pragma unroll
        for (int et = 0; et < 4; ++et)
            cfv[reg][et] = (ga < NATOM) ? xr[et * 16 + ln] : 0.f;
    }
    float bo[6];
    #pragma unroll
    for (int o = 0; o < 6; ++o) bo[o] = adjb[o];
    #pragma unroll
    for (int reg = 0; reg < 4; ++reg) {
        #pragma unroll
        for (int o = 0; o < 6; ++o) {
            float p = 0.f;
            #pragma unroll
            for (int et = 0; et < 4; ++et)
                p += acc[o * 4 + et][reg] * cfv[reg][et];
            p += __shfl_xor(p, 1); p += __shfl_xor(p, 2);
            p += __shfl_xor(p, 4); p += __shfl_xor(p, 8);
            if (ln == 0) qv[w * 16 + quad * 4 + reg][o] = p + bo[o];
        }
    }
    __syncthreads();
    if (t < 64) {
        int ga = p0 + t;
        if (ga < NATOM) {
            float q2[6];
            float mx = -1e30f;
            #pragma unroll
            for (int o2 = 0; o2 < 6; ++o2) {
                float acc2 = fc1b[o2];
                #pragma unroll
                for (int o = 0; o < 6; ++o) acc2 += qv[t][o] * fc1w[o * 6 + o2];
                q2[o2] = acc2; mx = fmaxf(mx, acc2);
            }
            float se = 0.f;
            #pragma unroll
            for (int o2 = 0; o2 < 6; ++o2) se += __expf(q2[o2] - mx);
            float lse = mx + __logf(se);
            #pragma unroll
            for (int o2 = 0; o2 < 6; ++o2) logp[(size_t)ga * 6 + o2] = q2[o2] - lse;
        }
    }
}

// ---------------- edge_prob broadcast write ----------------
__global__ void k_edge(const float* __restrict__ logp, float* __restrict__ out0) {
    int i4 = blockIdx.x * blockDim.x + threadIdx.x;
    if (i4 >= (NB * NPCC * NPCC * 6) / 4) return;
    int e = i4 * 4;
    int b = e / (NPCC * NPCC * 6);
    int rr = e - b * (NPCC * NPCC * 6);
    const float* lb = &logp[(size_t)b * NPCC * 6];
    float4 v;
    int r0 = rr % 300;       v.x = lb[r0];
    int r1 = (rr + 1) % 300; v.y = lb[r1];
    int r2 = (rr + 2) % 300; v.z = lb[r2];
    int r3 = (rr + 3) % 300; v.w = lb[r3];
    *reinterpret_cast<float4*>(&out0[e]) = v;
}

// ---------------- atom_feature = cf @ af_w + af_b ----------------
__global__ __launch_bounds__(256) void k_af(const float* __restrict__ x, const int* __restrict__ cidx,
                                            const float* __restrict__ afw,
                                            const float* __restrict__ afb,
                                            float* __restrict__ out1) {
    __shared__ float wl[AA * ORIGD];
    __shared__ float cfl[2][AA];
    int t = threadIdx.x;
    for (int i = t; i < AA * ORIGD; i += 256) wl[i] = afw[i];
    int p0 = blockIdx.x * 2;
    if (t < 128) {
        int a = t >> 6, e = t & 63;
        cfl[a][e] = x[(size_t)cidx[p0 + a] * AA + e];
    }
    __syncthreads();
    int a = t >> 7, c = t & 127;
    if (c < ORIGD) {
        float acc = afb[c];
        #pragma unroll 8
        for (int k = 0; k < AA; ++k)
            acc += cfl[a][k] * wl[k * ORIGD + c];
        out1[(size_t)(p0 + a) * ORIGD + c] = acc;
    }
}

extern "C" void kernel_launch(void* const* d_in, const int* in_sizes, int n_in,
                              void* d_out, int out_size, void* d_ws, size_t ws_size,
                              hipStream_t stream) {
    (void)in_sizes; (void)n_in; (void)out_size;
    const float* atom_fea  = (const float*)d_in[0];
    const float* nbr_fea   = (const float*)d_in[1];
    const int*   nbr_idx   = (const int*)d_in[2];
    const int*   cidx      = (const int*)d_in[3];
    const float* emb_w     = (const float*)d_in[4];
    const float* fc_full_w = (const float*)d_in[5];
    // d_in[6] fc_full_b: cancelled by batchnorm
    const float* bn1_g = (const float*)d_in[7];
    const float* bn1_b = (const float*)d_in[8];
    const float* bn2_g = (const float*)d_in[9];
    const float* bn2_b = (const float*)d_in[10];
    const float* adj_w = (const float*)d_in[11];
    const float* adj_b = (const float*)d_in[12];
    const float* fc1_w = (const float*)d_in[13];
    const float* fc1_b = (const float*)d_in[14];
    const float* af_w  = (const float*)d_in[15];
    const float* af_b  = (const float*)d_in[16];

    float* out0 = (float*)d_out;
    float* out1 = out0 + (size_t)NB * NPCC * NPCC * 6;

    float* ws = (float*)d_ws;
    float* x      = ws;                            // 3.2M
    float* summed = x + (size_t)NATOM * AA;        // 3.2M
    float* logp   = summed + (size_t)NATOM * AA;   // 0.3M
    float* stats1 = logp + (size_t)NATOM * 6;      // 256
    float* sc1    = stats1 + 256;                  // 256
    float* stats2 = sc1 + 256;                     // 128
    float* sc2    = stats2 + 128;                  // 128
    float* endf   = sc2 + 128;
    unsigned short* xb  = (unsigned short*)endf;   // 6.4MB
    unsigned short* Bt3 = xb + (size_t)NATOM * AA; // 3*128*72
    unsigned short* Bq  = Bt3 + 3 * 128 * 72;      // 384*72
    size_t goff = (((size_t)((char*)(Bq + 384 * 72) - (char*)d_ws)) + 255) & ~(size_t)255;
    uint2* gated = (uint2*)((char*)d_ws + goff);   // NPBLK * 8*BT uint2 = 153.6MB
    size_t noff = (goff + (size_t)NPBLK * 8 * BT * 8 + 255) & ~(size_t)255;
    unsigned short* nfb = (unsigned short*)((char*)d_ws + noff); // 86.4MB optional
    bool use_nfb = ws_size >= noff + (size_t)NEDGE * 72 * 2;

    k_embed<<<NATOM / 4, 256, 0, stream>>>(atom_fea, emb_w, x, xb);
    k_prepQ<<<108, 256, 0, stream>>>(adj_w, Bq);
    if (use_nfb) k_prepN<<<(NEDGE * 72) / 256, 256, 0, stream>>>(nbr_fea, nfb);
    for (int layer = 0; layer < 3; ++layer) {
        const float* W = fc_full_w + (size_t)layer * 169 * 128;
        k_zero<<<3, 256, 0, stream>>>(stats1, 768);
        k_prepB3<<<108, 256, 0, stream>>>(W, Bt3);
        if (use_nfb)
            k_passA<true><<<NPBLK, BT, 0, stream>>>(xb, nbr_fea, nfb, Bt3, nbr_idx, stats1, gated);
        else
            k_passA<false><<<NPBLK, BT, 0, stream>>>(xb, nbr_fea, nfb, Bt3, nbr_idx, stats1, gated);
        k_sc1<<<1, 128, 0, stream>>>(stats1, bn1_g + layer * 128, bn1_b + layer * 128, sc1);
        k_passBs<<<NPBLK, BT, 0, stream>>>(gated, sc1, summed, stats2);
        k_sc2<<<1, 64, 0, stream>>>(stats2, bn2_g + layer * 64, bn2_b + layer * 64, sc2);
        k_update<<<(NATOM * AA + 255) / 256, 256, 0, stream>>>(x, xb, summed, sc2);
    }
    k_q<<<(NATOM + 63) / 64, 256, 0, stream>>>(x, cidx, Bq, adj_b, fc1_w, fc1_b, logp);
    k_edge<<<((NB * NPCC * NPCC * 6) / 4 + 255) / 256, 256, 0, stream>>>(logp, out0);
    k_af<<<NATOM / 2, 256, 0, stream>>>(x, cidx, af_w, af_b, out1);
}